// Round 1
// baseline (591.810 us; speedup 1.0000x reference)
//
#include <hip/hip_runtime.h>

#define NND 50000
#define DIM 128
#define ADIM 64
#define NLBL 4
#define NEDGE 400000
#define NB (NLBL*NND)        // 200000 buckets
#define LE (NLBL*NEDGE)      // 1600000 edges
#define SCAN_NBLK 196        // ceil(200000/1024)

typedef _Float16 f16;
typedef _Float16 f16x2 __attribute__((ext_vector_type(2)));
typedef _Float16 f16x8 __attribute__((ext_vector_type(8)));
typedef float f32x4 __attribute__((ext_vector_type(4)));

__device__ __forceinline__ float sigmoid_(float x){ return 1.f/(1.f+__expf(-x)); }
__device__ __forceinline__ float tanh_(float x){ return 1.f - 2.f/(__expf(2.f*x)+1.f); }

// ---------------- prep: fp32->fp16 conversions + transposed weight layouts ----------------
__global__ void prep_kernel(const float* __restrict__ h, const float* __restrict__ x,
    const float* __restrict__ Wact,
    const float* __restrict__ Wz, const float* __restrict__ Wr, const float* __restrict__ Ww,
    const float* __restrict__ Uz, const float* __restrict__ Ur, const float* __restrict__ Uu,
    const float* __restrict__ rep,
    f16* __restrict__ hh, f16* __restrict__ xh,
    f16* __restrict__ wcat, f16* __restrict__ wzr, f16* __restrict__ wh, f16* __restrict__ wrep)
{
  const int TOT = NND*DIM + NND*ADIM + 65536 + 65536 + 32768 + 24576;
  for (int i = blockIdx.x*blockDim.x + threadIdx.x; i < TOT; i += gridDim.x*blockDim.x) {
    int j = i;
    if (j < NND*DIM) { hh[j] = (f16)h[j]; continue; }
    j -= NND*DIM;
    if (j < NND*ADIM) { xh[j] = (f16)x[j]; continue; }
    j -= NND*ADIM;
    if (j < 65536) {           // wcat[f][k], k = l*128+d ; = W_act[l][d][f]
      int f = j >> 9, k = j & 511; int l = k >> 7, d = k & 127;
      wcat[j] = (f16)Wact[l*16384 + d*128 + f]; continue;
    }
    j -= 65536;
    if (j < 65536) {           // wzr[jcol][k] : [[Wz,Wr],[Uz,Ur]] transposed
      int r = j >> 8, k = j & 255; float v;
      if (r < 128) v = (k < 128) ? Wz[k*128 + r] : Uz[(k-128)*128 + r];
      else { int rr = r-128; v = (k < 128) ? Wr[k*128 + rr] : Ur[(k-128)*128 + rr]; }
      wzr[j] = (f16)v; continue;
    }
    j -= 65536;
    if (j < 32768) {           // wh[jcol][k] : [[W],[U]] transposed
      int r = j >> 8, k = j & 255;
      wh[j] = (f16)((k < 128) ? Ww[k*128 + r] : Uu[(k-128)*128 + r]); continue;
    }
    j -= 32768;
    { int r = j / 192, k = j - r*192;   // wrep[jcol][k] = rep[k][jcol]
      wrep[j] = (f16)rep[k*128 + r]; }
  }
}

// ---------------- CSR build ----------------
__global__ void hist_kernel(const int* __restrict__ dst, int* __restrict__ cnt) {
  for (int i = blockIdx.x*blockDim.x + threadIdx.x; i < LE; i += gridDim.x*blockDim.x) {
    int l = i / NEDGE;
    atomicAdd(&cnt[l*NND + dst[i]], 1);
  }
}

__global__ void scan_reduce_kernel(const int* __restrict__ cnt, int* __restrict__ bsum) {
  __shared__ int s[256];
  int t = threadIdx.x; int base = blockIdx.x*1024;
  int v = 0;
  for (int i = t; i < 1024; i += 256) { int idx = base + i; if (idx < NB) v += cnt[idx]; }
  s[t] = v; __syncthreads();
  for (int o = 128; o > 0; o >>= 1) { if (t < o) s[t] += s[t+o]; __syncthreads(); }
  if (t == 0) bsum[blockIdx.x] = s[0];
}

__global__ void scan_top_kernel(int* __restrict__ bsum) {
  __shared__ int s[256];
  int t = threadIdx.x;
  int v = (t < SCAN_NBLK) ? bsum[t] : 0;
  s[t] = v; __syncthreads();
  for (int o = 1; o < 256; o <<= 1) { int u = (t >= o) ? s[t-o] : 0; __syncthreads(); s[t] += u; __syncthreads(); }
  if (t < SCAN_NBLK) bsum[t] = s[t] - v;   // exclusive
}

__global__ void scan_final_kernel(const int* __restrict__ cnt, const int* __restrict__ bsum,
                                  int* __restrict__ off, int* __restrict__ cur) {
  __shared__ int s[256];
  int t = threadIdx.x; int base = blockIdx.x*1024 + t*4;
  int c0=0,c1=0,c2=0,c3=0;
  if (base+0 < NB) c0 = cnt[base+0];
  if (base+1 < NB) c1 = cnt[base+1];
  if (base+2 < NB) c2 = cnt[base+2];
  if (base+3 < NB) c3 = cnt[base+3];
  int tot = c0+c1+c2+c3;
  s[t] = tot; __syncthreads();
  for (int o = 1; o < 256; o <<= 1) { int u = (t >= o) ? s[t-o] : 0; __syncthreads(); s[t] += u; __syncthreads(); }
  int pre = bsum[blockIdx.x] + s[t] - tot;
  if (base+0 < NB) { off[base+0]=pre; cur[base+0]=pre; } pre += c0;
  if (base+1 < NB) { off[base+1]=pre; cur[base+1]=pre; } pre += c1;
  if (base+2 < NB) { off[base+2]=pre; cur[base+2]=pre; } pre += c2;
  if (base+3 < NB) { off[base+3]=pre; cur[base+3]=pre; }
}

__global__ void fill_kernel(const int* __restrict__ src, const int* __restrict__ dst,
                            int* __restrict__ cur, int* __restrict__ csr) {
  for (int i = blockIdx.x*blockDim.x + threadIdx.x; i < LE; i += gridDim.x*blockDim.x) {
    int l = i / NEDGE;
    int pos = atomicAdd(&cur[l*NND + dst[i]], 1);
    csr[pos] = src[i];
  }
}

// ---------------- aggregate: g[n][l*128+c] = sum_{e: dst=n, lbl=l} h[src_e][c] ----------------
__global__ __launch_bounds__(256) void agg_kernel(const f16* __restrict__ hh,
    const int* __restrict__ csr, const int* __restrict__ off, const int* __restrict__ cnt,
    f16* __restrict__ g)
{
  int n = blockIdx.x;
  int l = threadIdx.x >> 6;
  int lane = threadIdx.x & 63;
  int b = l*NND + n;
  int beg = off[b], c = cnt[b];
  float ax = 0.f, ay = 0.f;
  for (int base = 0; base < c; base += 64) {
    int m = c - base; if (m > 64) m = 64;
    int my = 0;
    if (lane < m) my = csr[beg + base + lane];
    for (int j = 0; j < m; ++j) {
      int srcn = __shfl(my, j);
      f16x2 v = *(const f16x2*)(hh + (size_t)srcn*DIM + lane*2);
      ax += (float)v.x; ay += (float)v.y;
    }
  }
  f16x2 o2; o2.x = (f16)ax; o2.y = (f16)ay;
  *(f16x2*)(g + (size_t)n*512 + l*128 + lane*2) = o2;
}

// ---------------- GEMM: C[M x NC] = A[M x KT] * Wt^T, fused epilogues ----------------
// A split: cols [0,SPLIT) from A0 (row stride a0s halfs), [SPLIT,KT) from A1 (stride a1s).
// Wt stored transposed: [NC][KT] f16. BM=128, BN=128 (blockIdx.y picks 128-col panel).
template<int KT, int SPLIT, int EPI>
__global__ __launch_bounds__(256, 2) void gemm_kernel(
    const f16* __restrict__ A0, int a0s, const f16* __restrict__ A1, int a1s,
    const f16* __restrict__ Wt, const float* __restrict__ bias,
    const f16* __restrict__ X0, const f16* __restrict__ X1,
    f16* __restrict__ O0, f16* __restrict__ O1, float* __restrict__ OF, int M)
{
  constexpr int NK = KT / 64;
  __shared__ __align__(16) char smem[32768];   // A tile 16KB + B tile 16KB
  const int tid = threadIdx.x;
  const int w = tid >> 6, lane = tid & 63;
  const int wm = w >> 1, wn = w & 1;
  const int lr = lane >> 4, lc = lane & 15;
  const int bm0 = blockIdx.x * 128;
  const int by = blockIdx.y;
  const int tr = tid >> 3;   // 0..31
  const int tc = tid & 7;    // 16B chunk within 128B row

  f32x4 acc[4][4];
#pragma unroll
  for (int i = 0; i < 4; ++i)
#pragma unroll
    for (int j = 0; j < 4; ++j) acc[i][j] = (f32x4){0.f,0.f,0.f,0.f};

  auto loadAB = [&](int kt, uint4* a, uint4* b) {
    const int k0 = kt*64;
    const f16* s; int rs, kc;
    if (k0 < SPLIT) { s = A0; rs = a0s; kc = k0; } else { s = A1; rs = a1s; kc = k0 - SPLIT; }
#pragma unroll
    for (int p = 0; p < 4; ++p) {
      int rl = p*32 + tr; int gr = bm0 + rl;
      if (gr < M) a[p] = *(const uint4*)(s + (size_t)gr*rs + kc + tc*8);
      else a[p] = make_uint4(0u,0u,0u,0u);
    }
#pragma unroll
    for (int p = 0; p < 4; ++p) {
      int cl = p*32 + tr; int gc = by*128 + cl;
      b[p] = *(const uint4*)(Wt + (size_t)gc*KT + k0 + tc*8);
    }
  };

  uint4 av[4], bv[4];
  loadAB(0, av, bv);
#pragma unroll
  for (int kt = 0; kt < NK; ++kt) {
    __syncthreads();                       // previous compute done, LDS free
#pragma unroll
    for (int p = 0; p < 4; ++p) {
      int rl = p*32 + tr;
      int sw = (tc ^ (tr & 7)) * 16;       // XOR swizzle: kill 128B-stride bank conflicts
      *(uint4*)(smem + rl*128 + sw) = av[p];
      *(uint4*)(smem + 16384 + rl*128 + sw) = bv[p];
    }
    uint4 a2[4], b2[4];
    bool more = (kt+1 < NK);
    if (more) loadAB(kt+1, a2, b2);        // global latency hides under compute
    __syncthreads();
#pragma unroll
    for (int kk = 0; kk < 2; ++kk) {
      f16x8 af[4], bf[4];
      const int cb = ((kk*4 + lr) ^ (lc & 7)) * 16;
#pragma unroll
      for (int fm = 0; fm < 4; ++fm)
        af[fm] = *(const f16x8*)(smem + (wm*64 + fm*16 + lc)*128 + cb);
#pragma unroll
      for (int fn = 0; fn < 4; ++fn)
        bf[fn] = *(const f16x8*)(smem + 16384 + (wn*64 + fn*16 + lc)*128 + cb);
#pragma unroll
      for (int fm = 0; fm < 4; ++fm)
#pragma unroll
        for (int fn = 0; fn < 4; ++fn)
          acc[fm][fn] = __builtin_amdgcn_mfma_f32_16x16x32_f16(af[fm], bf[fn], acc[fm][fn], 0, 0, 0);
    }
    if (more) {
#pragma unroll
      for (int p = 0; p < 4; ++p) { av[p] = a2[p]; bv[p] = b2[p]; }
    }
  }

  // epilogue: C/D frag layout col=lane&15, row=(lane>>4)*4+t
#pragma unroll
  for (int fm = 0; fm < 4; ++fm) {
#pragma unroll
    for (int fn = 0; fn < 4; ++fn) {
      f32x4 v = acc[fm][fn];
      int col = by*128 + wn*64 + fn*16 + lc;
#pragma unroll
      for (int t = 0; t < 4; ++t) {
        int row = bm0 + wm*64 + fm*16 + lr*4 + t;
        if (row >= M) continue;
        float xv = v[t];
        if constexpr (EPI == 0) {          // a = msgs + b_act  -> f16
          O0[(size_t)row*128 + col] = (f16)(xv + bias[col]);
        } else if constexpr (EPI == 1) {   // z (by=0) / r*h (by=1)
          float sg = sigmoid_(xv);
          if (by == 0) O0[(size_t)row*128 + col] = (f16)sg;
          else { int c2 = col - 128;
                 O1[(size_t)row*128 + c2] = (f16)(sg * (float)X0[(size_t)row*128 + c2]); }
        } else if constexpr (EPI == 2) {   // h_new = (1-z)h + z*tanh(.)
          float th = tanh_(xv);
          float zz = (float)X0[(size_t)row*128 + col];
          float h0 = (float)X1[(size_t)row*128 + col];
          O0[(size_t)row*128 + col] = (f16)((1.f - zz)*h0 + zz*th);
        } else {                           // out = . + rep_bias -> fp32
          OF[(size_t)row*128 + col] = xv + bias[col];
        }
      }
    }
  }
}

// ---------------- launch ----------------
extern "C" void kernel_launch(void* const* d_in, const int* in_sizes, int n_in,
                              void* d_out, int out_size, void* d_ws, size_t ws_size,
                              hipStream_t stream) {
  const float* h    = (const float*)d_in[0];
  const float* x    = (const float*)d_in[1];
  const int*   esrc = (const int*)d_in[2];
  const int*   edst = (const int*)d_in[3];
  const float* Wact = (const float*)d_in[4];
  const float* bact = (const float*)d_in[5];
  const float* Wz   = (const float*)d_in[6];
  const float* Wr   = (const float*)d_in[7];
  const float* Ww   = (const float*)d_in[8];
  const float* Uz   = (const float*)d_in[9];
  const float* Ur   = (const float*)d_in[10];
  const float* Uu   = (const float*)d_in[11];
  const float* rep  = (const float*)d_in[12];
  const float* rbias= (const float*)d_in[13];
  float* out = (float*)d_out;

  char* ws = (char*)d_ws;
  size_t o = 0;
  auto alloc = [&](size_t bytes) { char* p = ws + o; o += (bytes + 255) & ~(size_t)255; return p; };
  f16* hh   = (f16*)alloc((size_t)NND*DIM*2);
  f16* xh   = (f16*)alloc((size_t)NND*ADIM*2);
  f16* wcat = (f16*)alloc(65536*2);
  f16* wzr  = (f16*)alloc(65536*2);
  f16* wh   = (f16*)alloc(32768*2);
  f16* wrep = (f16*)alloc(24576*2);
  int* cnt  = (int*)alloc((size_t)NB*4);
  int* off  = (int*)alloc((size_t)NB*4);
  int* cur  = (int*)alloc((size_t)NB*4);
  int* bsum = (int*)alloc(SCAN_NBLK*4);
  int* csr  = (int*)alloc((size_t)LE*4);
  f16* g    = (f16*)alloc((size_t)NND*512*2);       // 51.2 MB, dead after GEMM1
  f16* ah   = (f16*)alloc((size_t)NND*DIM*2);
  // alias z / r*h / h_new into the dead g region (each 12.8 MB)
  f16* zh   = (f16*)(char*)g;
  f16* rh   = (f16*)((char*)g + (size_t)NND*DIM*2);
  f16* hnew = (f16*)((char*)g + (size_t)2*NND*DIM*2);

  hipMemsetAsync(cnt, 0, (size_t)NB*4, stream);
  prep_kernel<<<2048, 256, 0, stream>>>(h, x, Wact, Wz, Wr, Ww, Uz, Ur, Uu, rep,
                                        hh, xh, wcat, wzr, wh, wrep);
  hist_kernel<<<2048, 256, 0, stream>>>(edst, cnt);
  scan_reduce_kernel<<<SCAN_NBLK, 256, 0, stream>>>(cnt, bsum);
  scan_top_kernel<<<1, 256, 0, stream>>>(bsum);
  scan_final_kernel<<<SCAN_NBLK, 256, 0, stream>>>(cnt, bsum, off, cur);
  fill_kernel<<<2048, 256, 0, stream>>>(esrc, edst, cur, csr);
  agg_kernel<<<NND, 256, 0, stream>>>(hh, csr, off, cnt, g);

  const int GM = (NND + 127) / 128;   // 391
  // a = g @ Wcat + b_act
  gemm_kernel<512,512,0><<<dim3(GM,1), 256, 0, stream>>>(g, 512, nullptr, 0, wcat, bact,
      nullptr, nullptr, ah, nullptr, nullptr, NND);
  // [z | r] = sigmoid([a,h] @ Wzr); store z and r*h
  gemm_kernel<256,128,1><<<dim3(GM,2), 256, 0, stream>>>(ah, 128, hh, 128, wzr, nullptr,
      hh, nullptr, zh, rh, nullptr, NND);
  // h_new = (1-z)h + z*tanh([a, r*h] @ Wh)
  gemm_kernel<256,128,2><<<dim3(GM,1), 256, 0, stream>>>(ah, 128, rh, 128, wh, nullptr,
      zh, hh, hnew, nullptr, nullptr, NND);
  // out = [h_new, x] @ rep + rep_bias
  gemm_kernel<192,128,3><<<dim3(GM,1), 256, 0, stream>>>(hnew, 128, xh, 64, wrep, rbias,
      nullptr, nullptr, nullptr, nullptr, out, NND);
}

// Round 7
// 472.553 us; speedup vs baseline: 1.2524x; 1.2524x over previous
//
#include <hip/hip_runtime.h>

#define NND 50000
#define DIM 128
#define ADIM 64
#define NLBL 4
#define NEDGE 400000
#define NB (NLBL*NND)        // 200000 buckets
#define LE (NLBL*NEDGE)      // 1600000 edges
#define SCAN_NBLK 196        // ceil(200000/1024)

typedef _Float16 f16;
typedef _Float16 f16x2 __attribute__((ext_vector_type(2)));
typedef _Float16 f16x8 __attribute__((ext_vector_type(8)));
typedef float f32x4 __attribute__((ext_vector_type(4)));

__device__ __forceinline__ float sigmoid_(float x){ return 1.f/(1.f+__expf(-x)); }
__device__ __forceinline__ float tanh_(float x){ return 1.f - 2.f/(__expf(2.f*x)+1.f); }

// ---------------- prep: fp32->fp16 conversions + transposed weight layouts ----------------
__global__ void prep_kernel(const float* __restrict__ h, const float* __restrict__ x,
    const float* __restrict__ Wact,
    const float* __restrict__ Wz, const float* __restrict__ Wr, const float* __restrict__ Ww,
    const float* __restrict__ Uz, const float* __restrict__ Ur, const float* __restrict__ Uu,
    const float* __restrict__ rep,
    f16* __restrict__ hh, f16* __restrict__ xh,
    f16* __restrict__ wcat, f16* __restrict__ wzr, f16* __restrict__ wh, f16* __restrict__ wrep)
{
  const int TOT = NND*DIM + NND*ADIM + 65536 + 65536 + 32768 + 24576;
  for (int i = blockIdx.x*blockDim.x + threadIdx.x; i < TOT; i += gridDim.x*blockDim.x) {
    int j = i;
    if (j < NND*DIM) { hh[j] = (f16)h[j]; continue; }
    j -= NND*DIM;
    if (j < NND*ADIM) { xh[j] = (f16)x[j]; continue; }
    j -= NND*ADIM;
    if (j < 65536) {           // wcat[f][k], k = l*128+d ; = W_act[l][d][f]
      int f = j >> 9, k = j & 511; int l = k >> 7, d = k & 127;
      wcat[j] = (f16)Wact[l*16384 + d*128 + f]; continue;
    }
    j -= 65536;
    if (j < 65536) {           // wzr[jcol][k] : [[Wz,Wr],[Uz,Ur]] transposed
      int r = j >> 8, k = j & 255; float v;
      if (r < 128) v = (k < 128) ? Wz[k*128 + r] : Uz[(k-128)*128 + r];
      else { int rr = r-128; v = (k < 128) ? Wr[k*128 + rr] : Ur[(k-128)*128 + rr]; }
      wzr[j] = (f16)v; continue;
    }
    j -= 65536;
    if (j < 32768) {           // wh[jcol][k] : [[W],[U]] transposed
      int r = j >> 8, k = j & 255;
      wh[j] = (f16)((k < 128) ? Ww[k*128 + r] : Uu[(k-128)*128 + r]); continue;
    }
    j -= 32768;
    { int r = j / 192, k = j - r*192;   // wrep[jcol][k] = rep[k][jcol]
      wrep[j] = (f16)rep[k*128 + r]; }
  }
}

// ---------------- CSR build ----------------
__global__ void hist_kernel(const int* __restrict__ dst, int* __restrict__ cnt) {
  for (int i = blockIdx.x*blockDim.x + threadIdx.x; i < LE; i += gridDim.x*blockDim.x) {
    int l = i / NEDGE;
    atomicAdd(&cnt[l*NND + dst[i]], 1);
  }
}

__global__ void scan_reduce_kernel(const int* __restrict__ cnt, int* __restrict__ bsum) {
  __shared__ int s[256];
  int t = threadIdx.x; int base = blockIdx.x*1024;
  int v = 0;
  for (int i = t; i < 1024; i += 256) { int idx = base + i; if (idx < NB) v += cnt[idx]; }
  s[t] = v; __syncthreads();
  for (int o = 128; o > 0; o >>= 1) { if (t < o) s[t] += s[t+o]; __syncthreads(); }
  if (t == 0) bsum[blockIdx.x] = s[0];
}

__global__ void scan_top_kernel(int* __restrict__ bsum) {
  __shared__ int s[256];
  int t = threadIdx.x;
  int v = (t < SCAN_NBLK) ? bsum[t] : 0;
  s[t] = v; __syncthreads();
  for (int o = 1; o < 256; o <<= 1) { int u = (t >= o) ? s[t-o] : 0; __syncthreads(); s[t] += u; __syncthreads(); }
  if (t < SCAN_NBLK) bsum[t] = s[t] - v;   // exclusive
}

__global__ void scan_final_kernel(const int* __restrict__ cnt, const int* __restrict__ bsum,
                                  int* __restrict__ off, int* __restrict__ cur) {
  __shared__ int s[256];
  int t = threadIdx.x; int base = blockIdx.x*1024 + t*4;
  int c0=0,c1=0,c2=0,c3=0;
  if (base+0 < NB) c0 = cnt[base+0];
  if (base+1 < NB) c1 = cnt[base+1];
  if (base+2 < NB) c2 = cnt[base+2];
  if (base+3 < NB) c3 = cnt[base+3];
  int tot = c0+c1+c2+c3;
  s[t] = tot; __syncthreads();
  for (int o = 1; o < 256; o <<= 1) { int u = (t >= o) ? s[t-o] : 0; __syncthreads(); s[t] += u; __syncthreads(); }
  int pre = bsum[blockIdx.x] + s[t] - tot;
  if (base+0 < NB) { off[base+0]=pre; cur[base+0]=pre; } pre += c0;
  if (base+1 < NB) { off[base+1]=pre; cur[base+1]=pre; } pre += c1;
  if (base+2 < NB) { off[base+2]=pre; cur[base+2]=pre; } pre += c2;
  if (base+3 < NB) { off[base+3]=pre; cur[base+3]=pre; }
}

__global__ void fill_kernel(const int* __restrict__ src, const int* __restrict__ dst,
                            int* __restrict__ cur, int* __restrict__ csr) {
  for (int i = blockIdx.x*blockDim.x + threadIdx.x; i < LE; i += gridDim.x*blockDim.x) {
    int l = i / NEDGE;
    int pos = atomicAdd(&cur[l*NND + dst[i]], 1);
    csr[pos] = src[i];
  }
}

// ---------------- aggregate: g[n][l*128+c] = sum_{e: dst=n, lbl=l} h[src_e][c] ----------------
// unrolled x4: 4 independent gathers in flight per wave (was 1 -> latency-bound)
__global__ __launch_bounds__(256) void agg_kernel(const f16* __restrict__ hh,
    const int* __restrict__ csr, const int* __restrict__ off, const int* __restrict__ cnt,
    f16* __restrict__ g)
{
  int n = blockIdx.x;
  int l = threadIdx.x >> 6;
  int lane = threadIdx.x & 63;
  int b = l*NND + n;
  int beg = off[b], c = cnt[b];
  const f16* hp = hh + lane*2;
  float ax = 0.f, ay = 0.f;
  for (int base = 0; base < c; base += 64) {
    int m = c - base; if (m > 64) m = 64;
    int my = 0;
    if (lane < m) my = csr[beg + base + lane];
    int j = 0;
    for (; j + 4 <= m; j += 4) {
      int s0 = __shfl(my, j), s1 = __shfl(my, j+1), s2 = __shfl(my, j+2), s3 = __shfl(my, j+3);
      f16x2 v0 = *(const f16x2*)(hp + (size_t)s0*DIM);
      f16x2 v1 = *(const f16x2*)(hp + (size_t)s1*DIM);
      f16x2 v2 = *(const f16x2*)(hp + (size_t)s2*DIM);
      f16x2 v3 = *(const f16x2*)(hp + (size_t)s3*DIM);
      ax += (float)v0.x + (float)v1.x + (float)v2.x + (float)v3.x;
      ay += (float)v0.y + (float)v1.y + (float)v2.y + (float)v3.y;
    }
    for (; j < m; ++j) {
      int s0 = __shfl(my, j);
      f16x2 v0 = *(const f16x2*)(hp + (size_t)s0*DIM);
      ax += (float)v0.x; ay += (float)v0.y;
    }
  }
  f16x2 o2; o2.x = (f16)ax; o2.y = (f16)ay;
  *(f16x2*)(g + (size_t)n*512 + l*128 + lane*2) = o2;
}

// ---------------- mega: entire post-agg chain, fused, per 64-row block ----------------
// phase1: a = g@Wcat + bact           (A direct from global, B from L2)  -> a_t LDS
// phase2: [z|r] = sigmoid([a,h]@Wzr)  (A from LDS, B from L2)            -> z_t, rh_t LDS
// phase3: hnew = (1-z)h + z*tanh([a,rh]@Wh)                               -> w_t LDS
// phase4: out = [hnew,x]@Wrep + rbias (x direct from global)              -> global fp32
__global__ __launch_bounds__(256, 2) void mega_kernel(
    const f16* __restrict__ g, const f16* __restrict__ hh, const f16* __restrict__ xh,
    const f16* __restrict__ wcat, const f16* __restrict__ wzr, const f16* __restrict__ whw,
    const f16* __restrict__ wrep, const float* __restrict__ bact, const float* __restrict__ rbias,
    float* __restrict__ out, int M)
{
  __shared__ __align__(16) char smem[65536];
  char* h_t = smem;             // [64][128] f16, swizzled
  char* a_t = smem + 16384;
  char* z_t = smem + 32768;
  char* w_t = smem + 49152;     // rh, later hnew
  const int tid = threadIdx.x;
  const int w = tid >> 6, lane = tid & 63;
  const int lr = lane >> 4, lc = lane & 15;
  const int r0 = blockIdx.x * 64;

  auto swz = [](int r, int c) { return r*256 + (((c ^ r) & 7) | (c & 8))*16; };

  // coop-load h tile (consumed first at phase2; barrier after phase1 covers it)
#pragma unroll
  for (int it = 0; it < 4; ++it) {
    int idx = it*256 + tid;
    int r = idx >> 4, c = idx & 15;
    int gr = r0 + r;
    uint4 vh = make_uint4(0u,0u,0u,0u);
    if (gr < M) vh = *(const uint4*)(hh + (size_t)gr*128 + c*8);
    *(uint4*)(h_t + swz(r, c)) = vh;
  }

  // ---- phase1: a = g @ wcat + bact ----
  {
    f32x4 acc[4][2];
#pragma unroll
    for (int i = 0; i < 4; ++i) { acc[i][0] = (f32x4){0,0,0,0}; acc[i][1] = (f32x4){0,0,0,0}; }
#pragma unroll
    for (int ks = 0; ks < 16; ++ks) {
      f16x8 af[4], bf[2];
#pragma unroll
      for (int fm = 0; fm < 4; ++fm) {
        int gr = r0 + fm*16 + lc;
        uint4 u = make_uint4(0u,0u,0u,0u);
        if (gr < M) u = *(const uint4*)(g + (size_t)gr*512 + ks*32 + lr*8);
        af[fm] = *reinterpret_cast<const f16x8*>(&u);
      }
#pragma unroll
      for (int fn = 0; fn < 2; ++fn)
        bf[fn] = *(const f16x8*)(wcat + (size_t)(w*32 + fn*16 + lc)*512 + ks*32 + lr*8);
#pragma unroll
      for (int fm = 0; fm < 4; ++fm)
#pragma unroll
        for (int fn = 0; fn < 2; ++fn)
          acc[fm][fn] = __builtin_amdgcn_mfma_f32_16x16x32_f16(af[fm], bf[fn], acc[fm][fn], 0, 0, 0);
    }
#pragma unroll
    for (int fm = 0; fm < 4; ++fm)
#pragma unroll
      for (int fn = 0; fn < 2; ++fn) {
        int col = w*32 + fn*16 + lc;
#pragma unroll
        for (int t = 0; t < 4; ++t) {
          int row = fm*16 + lr*4 + t;
          float v = acc[fm][fn][t] + bact[col];
          *(f16*)(a_t + swz(row, col >> 3) + (col & 7)*2) = (f16)v;
        }
      }
  }
  __syncthreads();

  // ---- phase2: [z|r] = sigmoid([a,h] @ wzr); waves 0,1 -> z, waves 2,3 -> rh ----
  {
    const int qc0 = w*64;
    f32x4 acc[4][4];
#pragma unroll
    for (int i = 0; i < 4; ++i)
#pragma unroll
      for (int j = 0; j < 4; ++j) acc[i][j] = (f32x4){0,0,0,0};
#pragma unroll
    for (int ks = 0; ks < 8; ++ks) {
      const char* asrc = (ks < 4) ? a_t : h_t;
      int cb = (ks & 3)*4 + lr;
      f16x8 af[4], bf[4];
#pragma unroll
      for (int fm = 0; fm < 4; ++fm)
        af[fm] = *(const f16x8*)(asrc + swz(fm*16 + lc, cb));
#pragma unroll
      for (int fn = 0; fn < 4; ++fn)
        bf[fn] = *(const f16x8*)(wzr + (size_t)(qc0 + fn*16 + lc)*256 + ks*32 + lr*8);
#pragma unroll
      for (int fm = 0; fm < 4; ++fm)
#pragma unroll
        for (int fn = 0; fn < 4; ++fn)
          acc[fm][fn] = __builtin_amdgcn_mfma_f32_16x16x32_f16(af[fm], bf[fn], acc[fm][fn], 0, 0, 0);
    }
#pragma unroll
    for (int fm = 0; fm < 4; ++fm)
#pragma unroll
      for (int fn = 0; fn < 4; ++fn) {
        int col = qc0 + fn*16 + lc;
#pragma unroll
        for (int t = 0; t < 4; ++t) {
          int row = fm*16 + lr*4 + t;
          float sg = sigmoid_(acc[fm][fn][t]);
          if (qc0 < 128) {
            *(f16*)(z_t + swz(row, col >> 3) + (col & 7)*2) = (f16)sg;
          } else {
            int c2 = col - 128;
            float h0 = (float)*(const f16*)(h_t + swz(row, c2 >> 3) + (c2 & 7)*2);
            *(f16*)(w_t + swz(row, c2 >> 3) + (c2 & 7)*2) = (f16)(sg * h0);
          }
        }
      }
  }
  __syncthreads();

  // ---- phase3: hnew = (1-z)h + z*tanh([a,rh] @ wh) ----
  {
    const int qc0 = w*32;
    f32x4 acc[4][2];
#pragma unroll
    for (int i = 0; i < 4; ++i) { acc[i][0] = (f32x4){0,0,0,0}; acc[i][1] = (f32x4){0,0,0,0}; }
#pragma unroll
    for (int ks = 0; ks < 8; ++ks) {
      const char* asrc = (ks < 4) ? a_t : w_t;
      int cb = (ks & 3)*4 + lr;
      f16x8 af[4], bf[2];
#pragma unroll
      for (int fm = 0; fm < 4; ++fm)
        af[fm] = *(const f16x8*)(asrc + swz(fm*16 + lc, cb));
#pragma unroll
      for (int fn = 0; fn < 2; ++fn)
        bf[fn] = *(const f16x8*)(whw + (size_t)(qc0 + fn*16 + lc)*256 + ks*32 + lr*8);
#pragma unroll
      for (int fm = 0; fm < 4; ++fm)
#pragma unroll
        for (int fn = 0; fn < 2; ++fn)
          acc[fm][fn] = __builtin_amdgcn_mfma_f32_16x16x32_f16(af[fm], bf[fn], acc[fm][fn], 0, 0, 0);
    }
    __syncthreads();   // all waves done reading rh before overwriting w_t with hnew
#pragma unroll
    for (int fm = 0; fm < 4; ++fm)
#pragma unroll
      for (int fn = 0; fn < 2; ++fn) {
        int col = qc0 + fn*16 + lc;
#pragma unroll
        for (int t = 0; t < 4; ++t) {
          int row = fm*16 + lr*4 + t;
          float th = tanh_(acc[fm][fn][t]);
          float zz = (float)*(const f16*)(z_t + swz(row, col >> 3) + (col & 7)*2);
          float h0 = (float)*(const f16*)(h_t + swz(row, col >> 3) + (col & 7)*2);
          *(f16*)(w_t + swz(row, col >> 3) + (col & 7)*2) = (f16)((1.f - zz)*h0 + zz*th);
        }
      }
  }
  __syncthreads();

  // ---- phase4: out = [hnew, x] @ wrep + rbias ----
  {
    const int qc0 = w*32;
    f32x4 acc[4][2];
#pragma unroll
    for (int i = 0; i < 4; ++i) { acc[i][0] = (f32x4){0,0,0,0}; acc[i][1] = (f32x4){0,0,0,0}; }
#pragma unroll
    for (int ks = 0; ks < 6; ++ks) {
      f16x8 af[4], bf[2];
      if (ks < 4) {
#pragma unroll
        for (int fm = 0; fm < 4; ++fm)
          af[fm] = *(const f16x8*)(w_t + swz(fm*16 + lc, ks*4 + lr));
      } else {
#pragma unroll
        for (int fm = 0; fm < 4; ++fm) {
          int gr = r0 + fm*16 + lc;
          uint4 u = make_uint4(0u,0u,0u,0u);
          if (gr < M) u = *(const uint4*)(xh + (size_t)gr*64 + (ks - 4)*32 + lr*8);
          af[fm] = *reinterpret_cast<const f16x8*>(&u);
        }
      }
#pragma unroll
      for (int fn = 0; fn < 2; ++fn)
        bf[fn] = *(const f16x8*)(wrep + (size_t)(qc0 + fn*16 + lc)*192 + ks*32 + lr*8);
#pragma unroll
      for (int fm = 0; fm < 4; ++fm)
#pragma unroll
        for (int fn = 0; fn < 2; ++fn)
          acc[fm][fn] = __builtin_amdgcn_mfma_f32_16x16x32_f16(af[fm], bf[fn], acc[fm][fn], 0, 0, 0);
    }
#pragma unroll
    for (int fm = 0; fm < 4; ++fm)
#pragma unroll
      for (int fn = 0; fn < 2; ++fn) {
        int col = qc0 + fn*16 + lc;
#pragma unroll
        for (int t = 0; t < 4; ++t) {
          int row = fm*16 + lr*4 + t;
          int grow = r0 + row;
          if (grow < M) out[(size_t)grow*128 + col] = acc[fm][fn][t] + rbias[col];
        }
      }
  }
}

// ---------------- launch ----------------
extern "C" void kernel_launch(void* const* d_in, const int* in_sizes, int n_in,
                              void* d_out, int out_size, void* d_ws, size_t ws_size,
                              hipStream_t stream) {
  const float* h    = (const float*)d_in[0];
  const float* x    = (const float*)d_in[1];
  const int*   esrc = (const int*)d_in[2];
  const int*   edst = (const int*)d_in[3];
  const float* Wact = (const float*)d_in[4];
  const float* bact = (const float*)d_in[5];
  const float* Wz   = (const float*)d_in[6];
  const float* Wr   = (const float*)d_in[7];
  const float* Ww   = (const float*)d_in[8];
  const float* Uz   = (const float*)d_in[9];
  const float* Ur   = (const float*)d_in[10];
  const float* Uu   = (const float*)d_in[11];
  const float* rep  = (const float*)d_in[12];
  const float* rbias= (const float*)d_in[13];
  float* out = (float*)d_out;

  char* ws = (char*)d_ws;
  size_t o = 0;
  auto alloc = [&](size_t bytes) { char* p = ws + o; o += (bytes + 255) & ~(size_t)255; return p; };
  f16* hh   = (f16*)alloc((size_t)NND*DIM*2);
  f16* xh   = (f16*)alloc((size_t)NND*ADIM*2);
  f16* wcat = (f16*)alloc(65536*2);
  f16* wzr  = (f16*)alloc(65536*2);
  f16* whw  = (f16*)alloc(32768*2);
  f16* wrep = (f16*)alloc(24576*2);
  int* cnt  = (int*)alloc((size_t)NB*4);
  int* off  = (int*)alloc((size_t)NB*4);
  int* cur  = (int*)alloc((size_t)NB*4);
  int* bsum = (int*)alloc(SCAN_NBLK*4);
  int* csr  = (int*)alloc((size_t)LE*4);
  f16* g    = (f16*)alloc((size_t)NND*512*2);       // 51.2 MB

  hipMemsetAsync(cnt, 0, (size_t)NB*4, stream);
  prep_kernel<<<2048, 256, 0, stream>>>(h, x, Wact, Wz, Wr, Ww, Uz, Ur, Uu, rep,
                                        hh, xh, wcat, wzr, whw, wrep);
  hist_kernel<<<2048, 256, 0, stream>>>(edst, cnt);
  scan_reduce_kernel<<<SCAN_NBLK, 256, 0, stream>>>(cnt, bsum);
  scan_top_kernel<<<1, 256, 0, stream>>>(bsum);
  scan_final_kernel<<<SCAN_NBLK, 256, 0, stream>>>(cnt, bsum, off, cur);
  fill_kernel<<<2048, 256, 0, stream>>>(esrc, edst, cur, csr);
  agg_kernel<<<NND, 256, 0, stream>>>(hh, csr, off, cnt, g);

  const int GB = (NND + 63) / 64;   // 782
  mega_kernel<<<GB, 256, 0, stream>>>(g, hh, xh, wcat, wzr, whw, wrep, bact, rbias, out, NND);
}

// Round 10
// 439.452 us; speedup vs baseline: 1.3467x; 1.0753x over previous
//
#include <hip/hip_runtime.h>

#define NND 50000
#define DIM 128
#define ADIM 64
#define NLBL 4
#define NEDGE 400000
#define NB (NLBL*NND)        // 200000 buckets
#define LE (NLBL*NEDGE)      // 1600000 edges
#define SCAN_NBLK 196        // ceil(200000/1024)
#define NSLICE 8             // dst slices, pinned to XCDs via blockIdx&7
#define SLICEW 6250          // NND / NSLICE
#define NCHUNK 256           // edge chunks
#define CPE (LE/NCHUNK)      // 6250 edges per chunk

typedef _Float16 f16;
typedef _Float16 f16x2 __attribute__((ext_vector_type(2)));
typedef _Float16 f16x8 __attribute__((ext_vector_type(8)));
typedef float f32x4 __attribute__((ext_vector_type(4)));

__device__ __forceinline__ float sigmoid_(float x){ return 1.f/(1.f+__expf(-x)); }
__device__ __forceinline__ float tanh_(float x){ return 1.f - 2.f/(__expf(2.f*x)+1.f); }

// ---------------- prep: fp32->fp16 conversions + transposed weight layouts ----------------
__global__ void prep_kernel(const float* __restrict__ h, const float* __restrict__ x,
    const float* __restrict__ Wact,
    const float* __restrict__ Wz, const float* __restrict__ Wr, const float* __restrict__ Ww,
    const float* __restrict__ Uz, const float* __restrict__ Ur, const float* __restrict__ Uu,
    const float* __restrict__ rep,
    f16* __restrict__ hh, f16* __restrict__ xh,
    f16* __restrict__ wcat, f16* __restrict__ wzr, f16* __restrict__ wh, f16* __restrict__ wrep)
{
  const int TOT = NND*DIM + NND*ADIM + 65536 + 65536 + 32768 + 24576;
  for (int i = blockIdx.x*blockDim.x + threadIdx.x; i < TOT; i += gridDim.x*blockDim.x) {
    int j = i;
    if (j < NND*DIM) { hh[j] = (f16)h[j]; continue; }
    j -= NND*DIM;
    if (j < NND*ADIM) { xh[j] = (f16)x[j]; continue; }
    j -= NND*ADIM;
    if (j < 65536) {           // wcat[f][k], k = l*128+d ; = W_act[l][d][f]
      int f = j >> 9, k = j & 511; int l = k >> 7, d = k & 127;
      wcat[j] = (f16)Wact[l*16384 + d*128 + f]; continue;
    }
    j -= 65536;
    if (j < 65536) {           // wzr[jcol][k] : [[Wz,Wr],[Uz,Ur]] transposed
      int r = j >> 8, k = j & 255; float v;
      if (r < 128) v = (k < 128) ? Wz[k*128 + r] : Uz[(k-128)*128 + r];
      else { int rr = r-128; v = (k < 128) ? Wr[k*128 + rr] : Ur[(k-128)*128 + rr]; }
      wzr[j] = (f16)v; continue;
    }
    j -= 65536;
    if (j < 32768) {           // wh[jcol][k] : [[W],[U]] transposed
      int r = j >> 8, k = j & 255;
      wh[j] = (f16)((k < 128) ? Ww[k*128 + r] : Uu[(k-128)*128 + r]); continue;
    }
    j -= 32768;
    { int r = j / 192, k = j - r*192;   // wrep[jcol][k] = rep[k][jcol]
      wrep[j] = (f16)rep[k*128 + r]; }
  }
}

// ---------------- CSR build (dst-sliced: block = chunk*8 + slice; slice -> XCD via &7) ------
// Each block scans its edge chunk, handles only dst in its slice. Confines cnt/cur/csr
// writes for a slice to one XCD's L2 -> full-line accumulation, no 16x write amplification.
__global__ void hist_kernel(const int* __restrict__ dst, int* __restrict__ cnt) {
  const int slice = blockIdx.x & (NSLICE-1);
  const int chunk = blockIdx.x >> 3;
  const int lo = slice * SLICEW, hi = lo + SLICEW;
  const int base = chunk * CPE, end = base + CPE;
  for (int i = base + threadIdx.x; i < end; i += blockDim.x) {
    int d = dst[i];
    if (d >= lo && d < hi) {
      int l = i / NEDGE;
      atomicAdd(&cnt[l*NND + d], 1);
    }
  }
}

__global__ void scan_reduce_kernel(const int* __restrict__ cnt, int* __restrict__ bsum) {
  __shared__ int s[256];
  int t = threadIdx.x; int base = blockIdx.x*1024;
  int v = 0;
  for (int i = t; i < 1024; i += 256) { int idx = base + i; if (idx < NB) v += cnt[idx]; }
  s[t] = v; __syncthreads();
  for (int o = 128; o > 0; o >>= 1) { if (t < o) s[t] += s[t+o]; __syncthreads(); }
  if (t == 0) bsum[blockIdx.x] = s[0];
}

__global__ void scan_top_kernel(int* __restrict__ bsum) {
  __shared__ int s[256];
  int t = threadIdx.x;
  int v = (t < SCAN_NBLK) ? bsum[t] : 0;
  s[t] = v; __syncthreads();
  for (int o = 1; o < 256; o <<= 1) { int u = (t >= o) ? s[t-o] : 0; __syncthreads(); s[t] += u; __syncthreads(); }
  if (t < SCAN_NBLK) bsum[t] = s[t] - v;   // exclusive
}

__global__ void scan_final_kernel(const int* __restrict__ cnt, const int* __restrict__ bsum,
                                  int* __restrict__ off, int* __restrict__ cur) {
  __shared__ int s[256];
  int t = threadIdx.x; int base = blockIdx.x*1024 + t*4;
  int c0=0,c1=0,c2=0,c3=0;
  if (base+0 < NB) c0 = cnt[base+0];
  if (base+1 < NB) c1 = cnt[base+1];
  if (base+2 < NB) c2 = cnt[base+2];
  if (base+3 < NB) c3 = cnt[base+3];
  int tot = c0+c1+c2+c3;
  s[t] = tot; __syncthreads();
  for (int o = 1; o < 256; o <<= 1) { int u = (t >= o) ? s[t-o] : 0; __syncthreads(); s[t] += u; __syncthreads(); }
  int pre = bsum[blockIdx.x] + s[t] - tot;
  if (base+0 < NB) { off[base+0]=pre; cur[base+0]=pre; } pre += c0;
  if (base+1 < NB) { off[base+1]=pre; cur[base+1]=pre; } pre += c1;
  if (base+2 < NB) { off[base+2]=pre; cur[base+2]=pre; } pre += c2;
  if (base+3 < NB) { off[base+3]=pre; cur[base+3]=pre; }
}

__global__ void fill_kernel(const int* __restrict__ src, const int* __restrict__ dst,
                            int* __restrict__ cur, int* __restrict__ csr) {
  const int slice = blockIdx.x & (NSLICE-1);
  const int chunk = blockIdx.x >> 3;
  const int lo = slice * SLICEW, hi = lo + SLICEW;
  const int base = chunk * CPE, end = base + CPE;
  for (int i = base + threadIdx.x; i < end; i += blockDim.x) {
    int d = dst[i];
    if (d >= lo && d < hi) {
      int l = i / NEDGE;
      int pos = atomicAdd(&cur[l*NND + d], 1);
      csr[pos] = src[i];
    }
  }
}

// ---------------- aggregate: g[n][l*128+c] = sum_{e: dst=n, lbl=l} h[src_e][c] ----------------
// unrolled x4: 4 independent gathers in flight per wave (was 1 -> latency-bound)
__global__ __launch_bounds__(256) void agg_kernel(const f16* __restrict__ hh,
    const int* __restrict__ csr, const int* __restrict__ off, const int* __restrict__ cnt,
    f16* __restrict__ g)
{
  int n = blockIdx.x;
  int l = threadIdx.x >> 6;
  int lane = threadIdx.x & 63;
  int b = l*NND + n;
  int beg = off[b], c = cnt[b];
  const f16* hp = hh + lane*2;
  float ax = 0.f, ay = 0.f;
  for (int base = 0; base < c; base += 64) {
    int m = c - base; if (m > 64) m = 64;
    int my = 0;
    if (lane < m) my = csr[beg + base + lane];
    int j = 0;
    for (; j + 4 <= m; j += 4) {
      int s0 = __shfl(my, j), s1 = __shfl(my, j+1), s2 = __shfl(my, j+2), s3 = __shfl(my, j+3);
      f16x2 v0 = *(const f16x2*)(hp + (size_t)s0*DIM);
      f16x2 v1 = *(const f16x2*)(hp + (size_t)s1*DIM);
      f16x2 v2 = *(const f16x2*)(hp + (size_t)s2*DIM);
      f16x2 v3 = *(const f16x2*)(hp + (size_t)s3*DIM);
      ax += (float)v0.x + (float)v1.x + (float)v2.x + (float)v3.x;
      ay += (float)v0.y + (float)v1.y + (float)v2.y + (float)v3.y;
    }
    for (; j < m; ++j) {
      int s0 = __shfl(my, j);
      f16x2 v0 = *(const f16x2*)(hp + (size_t)s0*DIM);
      ax += (float)v0.x; ay += (float)v0.y;
    }
  }
  f16x2 o2; o2.x = (f16)ax; o2.y = (f16)ay;
  *(f16x2*)(g + (size_t)n*512 + l*128 + lane*2) = o2;
}

// ---------------- mega: entire post-agg chain, fused, per 64-row block ----------------
// phase1: a = g@Wcat + bact           (A direct from global, B from L2)  -> a_t LDS
// phase2: [z|r] = sigmoid([a,h]@Wzr)  (A from LDS, B from L2)            -> z_t, rh_t LDS
// phase3: hnew = (1-z)h + z*tanh([a,rh]@Wh)                               -> w_t LDS
// phase4: out = [hnew,x]@Wrep + rbias (x direct from global)              -> global fp32
__global__ __launch_bounds__(256, 2) void mega_kernel(
    const f16* __restrict__ g, const f16* __restrict__ hh, const f16* __restrict__ xh,
    const f16* __restrict__ wcat, const f16* __restrict__ wzr, const f16* __restrict__ whw,
    const f16* __restrict__ wrep, const float* __restrict__ bact, const float* __restrict__ rbias,
    float* __restrict__ out, int M)
{
  __shared__ __align__(16) char smem[65536];
  char* h_t = smem;             // [64][128] f16, swizzled
  char* a_t = smem + 16384;
  char* z_t = smem + 32768;
  char* w_t = smem + 49152;     // rh, later hnew
  const int tid = threadIdx.x;
  const int w = tid >> 6, lane = tid & 63;
  const int lr = lane >> 4, lc = lane & 15;
  const int r0 = blockIdx.x * 64;

  auto swz = [](int r, int c) { return r*256 + (((c ^ r) & 7) | (c & 8))*16; };

  // coop-load h tile (consumed first at phase2; barrier after phase1 covers it)
#pragma unroll
  for (int it = 0; it < 4; ++it) {
    int idx = it*256 + tid;
    int r = idx >> 4, c = idx & 15;
    int gr = r0 + r;
    uint4 vh = make_uint4(0u,0u,0u,0u);
    if (gr < M) vh = *(const uint4*)(hh + (size_t)gr*128 + c*8);
    *(uint4*)(h_t + swz(r, c)) = vh;
  }

  // ---- phase1: a = g @ wcat + bact ----
  {
    f32x4 acc[4][2];
#pragma unroll
    for (int i = 0; i < 4; ++i) { acc[i][0] = (f32x4){0,0,0,0}; acc[i][1] = (f32x4){0,0,0,0}; }
#pragma unroll
    for (int ks = 0; ks < 16; ++ks) {
      f16x8 af[4], bf[2];
#pragma unroll
      for (int fm = 0; fm < 4; ++fm) {
        int gr = r0 + fm*16 + lc;
        uint4 u = make_uint4(0u,0u,0u,0u);
        if (gr < M) u = *(const uint4*)(g + (size_t)gr*512 + ks*32 + lr*8);
        af[fm] = *reinterpret_cast<const f16x8*>(&u);
      }
#pragma unroll
      for (int fn = 0; fn < 2; ++fn)
        bf[fn] = *(const f16x8*)(wcat + (size_t)(w*32 + fn*16 + lc)*512 + ks*32 + lr*8);
#pragma unroll
      for (int fm = 0; fm < 4; ++fm)
#pragma unroll
        for (int fn = 0; fn < 2; ++fn)
          acc[fm][fn] = __builtin_amdgcn_mfma_f32_16x16x32_f16(af[fm], bf[fn], acc[fm][fn], 0, 0, 0);
    }
#pragma unroll
    for (int fm = 0; fm < 4; ++fm)
#pragma unroll
      for (int fn = 0; fn < 2; ++fn) {
        int col = w*32 + fn*16 + lc;
#pragma unroll
        for (int t = 0; t < 4; ++t) {
          int row = fm*16 + lr*4 + t;
          float v = acc[fm][fn][t] + bact[col];
          *(f16*)(a_t + swz(row, col >> 3) + (col & 7)*2) = (f16)v;
        }
      }
  }
  __syncthreads();

  // ---- phase2: [z|r] = sigmoid([a,h] @ wzr); waves 0,1 -> z, waves 2,3 -> rh ----
  {
    const int qc0 = w*64;
    f32x4 acc[4][4];
#pragma unroll
    for (int i = 0; i < 4; ++i)
#pragma unroll
      for (int j = 0; j < 4; ++j) acc[i][j] = (f32x4){0,0,0,0};
#pragma unroll
    for (int ks = 0; ks < 8; ++ks) {
      const char* asrc = (ks < 4) ? a_t : h_t;
      int cb = (ks & 3)*4 + lr;
      f16x8 af[4], bf[4];
#pragma unroll
      for (int fm = 0; fm < 4; ++fm)
        af[fm] = *(const f16x8*)(asrc + swz(fm*16 + lc, cb));
#pragma unroll
      for (int fn = 0; fn < 4; ++fn)
        bf[fn] = *(const f16x8*)(wzr + (size_t)(qc0 + fn*16 + lc)*256 + ks*32 + lr*8);
#pragma unroll
      for (int fm = 0; fm < 4; ++fm)
#pragma unroll
        for (int fn = 0; fn < 4; ++fn)
          acc[fm][fn] = __builtin_amdgcn_mfma_f32_16x16x32_f16(af[fm], bf[fn], acc[fm][fn], 0, 0, 0);
    }
#pragma unroll
    for (int fm = 0; fm < 4; ++fm)
#pragma unroll
      for (int fn = 0; fn < 4; ++fn) {
        int col = qc0 + fn*16 + lc;
#pragma unroll
        for (int t = 0; t < 4; ++t) {
          int row = fm*16 + lr*4 + t;
          float sg = sigmoid_(acc[fm][fn][t]);
          if (qc0 < 128) {
            *(f16*)(z_t + swz(row, col >> 3) + (col & 7)*2) = (f16)sg;
          } else {
            int c2 = col - 128;
            float h0 = (float)*(const f16*)(h_t + swz(row, c2 >> 3) + (c2 & 7)*2);
            *(f16*)(w_t + swz(row, c2 >> 3) + (c2 & 7)*2) = (f16)(sg * h0);
          }
        }
      }
  }
  __syncthreads();

  // ---- phase3: hnew = (1-z)h + z*tanh([a,rh] @ wh) ----
  {
    const int qc0 = w*32;
    f32x4 acc[4][2];
#pragma unroll
    for (int i = 0; i < 4; ++i) { acc[i][0] = (f32x4){0,0,0,0}; acc[i][1] = (f32x4){0,0,0,0}; }
#pragma unroll
    for (int ks = 0; ks < 8; ++ks) {
      const char* asrc = (ks < 4) ? a_t : w_t;
      int cb = (ks & 3)*4 + lr;
      f16x8 af[4], bf[2];
#pragma unroll
      for (int fm = 0; fm < 4; ++fm)
        af[fm] = *(const f16x8*)(asrc + swz(fm*16 + lc, cb));
#pragma unroll
      for (int fn = 0; fn < 2; ++fn)
        bf[fn] = *(const f16x8*)(whw + (size_t)(qc0 + fn*16 + lc)*256 + ks*32 + lr*8);
#pragma unroll
      for (int fm = 0; fm < 4; ++fm)
#pragma unroll
        for (int fn = 0; fn < 2; ++fn)
          acc[fm][fn] = __builtin_amdgcn_mfma_f32_16x16x32_f16(af[fm], bf[fn], acc[fm][fn], 0, 0, 0);
    }
    __syncthreads();   // all waves done reading rh before overwriting w_t with hnew
#pragma unroll
    for (int fm = 0; fm < 4; ++fm)
#pragma unroll
      for (int fn = 0; fn < 2; ++fn) {
        int col = qc0 + fn*16 + lc;
#pragma unroll
        for (int t = 0; t < 4; ++t) {
          int row = fm*16 + lr*4 + t;
          float th = tanh_(acc[fm][fn][t]);
          float zz = (float)*(const f16*)(z_t + swz(row, col >> 3) + (col & 7)*2);
          float h0 = (float)*(const f16*)(h_t + swz(row, col >> 3) + (col & 7)*2);
          *(f16*)(w_t + swz(row, col >> 3) + (col & 7)*2) = (f16)((1.f - zz)*h0 + zz*th);
        }
      }
  }
  __syncthreads();

  // ---- phase4: out = [hnew, x] @ wrep + rbias ----
  {
    const int qc0 = w*32;
    f32x4 acc[4][2];
#pragma unroll
    for (int i = 0; i < 4; ++i) { acc[i][0] = (f32x4){0,0,0,0}; acc[i][1] = (f32x4){0,0,0,0}; }
#pragma unroll
    for (int ks = 0; ks < 6; ++ks) {
      f16x8 af[4], bf[2];
      if (ks < 4) {
#pragma unroll
        for (int fm = 0; fm < 4; ++fm)
          af[fm] = *(const f16x8*)(w_t + swz(fm*16 + lc, ks*4 + lr));
      } else {
#pragma unroll
        for (int fm = 0; fm < 4; ++fm) {
          int gr = r0 + fm*16 + lc;
          uint4 u = make_uint4(0u,0u,0u,0u);
          if (gr < M) u = *(const uint4*)(xh + (size_t)gr*64 + (ks - 4)*32 + lr*8);
          af[fm] = *reinterpret_cast<const f16x8*>(&u);
        }
      }
#pragma unroll
      for (int fn = 0; fn < 2; ++fn)
        bf[fn] = *(const f16x8*)(wrep + (size_t)(qc0 + fn*16 + lc)*192 + ks*32 + lr*8);
#pragma unroll
      for (int fm = 0; fm < 4; ++fm)
#pragma unroll
        for (int fn = 0; fn < 2; ++fn)
          acc[fm][fn] = __builtin_amdgcn_mfma_f32_16x16x32_f16(af[fm], bf[fn], acc[fm][fn], 0, 0, 0);
    }
#pragma unroll
    for (int fm = 0; fm < 4; ++fm)
#pragma unroll
      for (int fn = 0; fn < 2; ++fn) {
        int col = qc0 + fn*16 + lc;
#pragma unroll
        for (int t = 0; t < 4; ++t) {
          int row = fm*16 + lr*4 + t;
          int grow = r0 + row;
          if (grow < M) out[(size_t)grow*128 + col] = acc[fm][fn][t] + rbias[col];
        }
      }
  }
}

// ---------------- launch ----------------
extern "C" void kernel_launch(void* const* d_in, const int* in_sizes, int n_in,
                              void* d_out, int out_size, void* d_ws, size_t ws_size,
                              hipStream_t stream) {
  const float* h    = (const float*)d_in[0];
  const float* x    = (const float*)d_in[1];
  const int*   esrc = (const int*)d_in[2];
  const int*   edst = (const int*)d_in[3];
  const float* Wact = (const float*)d_in[4];
  const float* bact = (const float*)d_in[5];
  const float* Wz   = (const float*)d_in[6];
  const float* Wr   = (const float*)d_in[7];
  const float* Ww   = (const float*)d_in[8];
  const float* Uz   = (const float*)d_in[9];
  const float* Ur   = (const float*)d_in[10];
  const float* Uu   = (const float*)d_in[11];
  const float* rep  = (const float*)d_in[12];
  const float* rbias= (const float*)d_in[13];
  float* out = (float*)d_out;

  char* ws = (char*)d_ws;
  size_t o = 0;
  auto alloc = [&](size_t bytes) { char* p = ws + o; o += (bytes + 255) & ~(size_t)255; return p; };
  f16* hh   = (f16*)alloc((size_t)NND*DIM*2);
  f16* xh   = (f16*)alloc((size_t)NND*ADIM*2);
  f16* wcat = (f16*)alloc(65536*2);
  f16* wzr  = (f16*)alloc(65536*2);
  f16* whw  = (f16*)alloc(32768*2);
  f16* wrep = (f16*)alloc(24576*2);
  int* cnt  = (int*)alloc((size_t)NB*4);
  int* off  = (int*)alloc((size_t)NB*4);
  int* cur  = (int*)alloc((size_t)NB*4);
  int* bsum = (int*)alloc(SCAN_NBLK*4);
  int* csr  = (int*)alloc((size_t)LE*4);
  f16* g    = (f16*)alloc((size_t)NND*512*2);       // 51.2 MB

  hipMemsetAsync(cnt, 0, (size_t)NB*4, stream);
  prep_kernel<<<2048, 256, 0, stream>>>(h, x, Wact, Wz, Wr, Ww, Uz, Ur, Uu, rep,
                                        hh, xh, wcat, wzr, whw, wrep);
  hist_kernel<<<NCHUNK*NSLICE, 256, 0, stream>>>(edst, cnt);
  scan_reduce_kernel<<<SCAN_NBLK, 256, 0, stream>>>(cnt, bsum);
  scan_top_kernel<<<1, 256, 0, stream>>>(bsum);
  scan_final_kernel<<<SCAN_NBLK, 256, 0, stream>>>(cnt, bsum, off, cur);
  fill_kernel<<<NCHUNK*NSLICE, 256, 0, stream>>>(esrc, edst, cur, csr);
  agg_kernel<<<NND, 256, 0, stream>>>(hh, csr, off, cnt, g);

  const int GB = (NND + 63) / 64;   // 782
  mega_kernel<<<GB, 256, 0, stream>>>(g, hh, xh, wcat, wzr, whw, wrep, bact, rbias, out, NND);
}